// Round 9
// baseline (358.416 us; speedup 1.0000x reference)
//
#include <hip/hip_runtime.h>
#include <math.h>

#define B_ 2
#define N_ 25000
#define E_ 400000
#define D_ 128
#define NRBF 64

#define TPB 256               // 4 waves
#define NTILES 25             // tiles per wave; 16 edges per wave-tile
#define WCH 400               // edges per wave
#define GCH 100               // edges per (wave, lane-quad) contiguous chunk
#define EPB (4 * WCH)         // 1600 edges per block
#define NBLK (E_ / EPB)       // 250 blocks per batch

typedef short bf8    __attribute__((ext_vector_type(8)));   // MFMA A/B frag
typedef float f32x4  __attribute__((ext_vector_type(4)));   // MFMA C/D frag
typedef float vf8    __attribute__((ext_vector_type(8)));
typedef unsigned int u32;
typedef u32 u32x4    __attribute__((ext_vector_type(4)));

// pack two f32 -> u32 [bf16(hi):bf16(lo)], round-half-up (hot path)
__device__ __forceinline__ u32 pack2(float hi, float lo) {
    union { float f; u32 u; } a, b; a.f = hi; b.f = lo;
    return __builtin_amdgcn_perm(a.u + 0x8000u, b.u + 0x8000u, 0x07060302u);
}
__device__ __forceinline__ short f2bf(float f) {   // RNE, one-time paths
    union { float f; u32 u; } v; v.f = f;
    return (short)((v.u + 0x7FFFu + ((v.u >> 16) & 1u)) >> 16);
}
// shifted softplus: softplus(x) - ln(2)
__device__ __forceinline__ float ssp(float x) {
    float t = __expf(-fabsf(x));
    float l = __logf(1.0f + t);
    return (fmaxf(x, 0.0f) - 0.69314718056f) + l;
}

__global__ __launch_bounds__(TPB, 2)
void cfconv_kernel(const float* __restrict__ af,      // [B,N,D]
                   const float* __restrict__ dist,    // [B,E]
                   const int*   __restrict__ idx_j,   // [E]
                   const int*   __restrict__ seg_i,   // [E] (sorted)
                   const float* __restrict__ centers, // [NRBF]
                   const float* __restrict__ gam,     // [NRBF]
                   const float* __restrict__ W1,      // [NRBF,D]
                   const float* __restrict__ b1,      // [D]
                   const float* __restrict__ W2,      // [D,D]
                   const float* __restrict__ b2,      // [D]
                   float* __restrict__ out)           // [B,N,D]
{
    const int t    = threadIdx.x;
    const int lane = t & 63;
    const int w    = t >> 6;          // wave 0..3
    const int g    = lane >> 4;       // quad 0..3
    const int c0   = lane & 15;
    const int b    = blockIdx.y;
    const int e0   = blockIdx.x * EPB;

    // fragment-ready bf16 weights, PERMUTED columns:
    //   physical col c carries logical col 8*(c&15) + (c>>4)
    //   layout [cc][g][c][j], B[k][.], k = cc*32 + g*8 + j
    __shared__ __align__(16) short W1f[2 * 4 * D_ * 8];     // 16 KB
    __shared__ __align__(16) short W2f[4 * 4 * D_ * 8];     // 32 KB
    // per-wave h1, A-frag order: A2[w][kb][m ^ (kb&7)][j] = h1[m][8*kb+j]  (16 KB)
    __shared__ __align__(16) short A2[4][16][16][8];
    // small params in LDS so they are per-tile transients, not persistent VGPRs
    __shared__ __align__(16) float prm[2][NRBF];            // [0]=gam*log2e, [1]=centers
    __shared__ __align__(16) float bia[2][D_];              // b1, b2 (logical order)

    // ---- one-time staging
    for (int i = t; i < NRBF * D_; i += TPB) {
        const int k = i >> 7, c = i & 127;
        W1f[(((k >> 5) * 4 + ((k >> 3) & 3)) * D_ + c) * 8 + (k & 7)] =
            f2bf(W1[(size_t)k * D_ + 8 * (c & 15) + (c >> 4)]);
    }
    for (int i = t; i < D_ * D_; i += TPB) {
        const int k = i >> 7, c = i & 127;
        W2f[(((k >> 5) * 4 + ((k >> 3) & 3)) * D_ + c) * 8 + (k & 7)] =
            f2bf(W2[(size_t)k * D_ + 8 * (c & 15) + (c >> 4)]);
    }
    if (t < NRBF) { prm[0][t] = gam[t] * 1.44269504f; prm[1][t] = centers[t]; }
    if (t >= 128 && t < 256) { bia[0][t - 128] = b1[t - 128]; bia[1][t - 128] = b2[t - 128]; }
    __syncthreads();

    const float* dist_b = dist + (size_t)b * E_;
    const float* af_b   = af   + (size_t)b * N_ * D_;
    float*       out_b  = out  + (size_t)b * N_ * D_;

    const int eArow = e0 + w * WCH + (c0 >> 2) * GCH + (c0 & 3);  // A-row m=c0
    const int ebase = e0 + w * WCH + g * GCH;                     // epilogue quad

    int cur_seg = -1;
    vf8 pend = (vf8)0.0f;

    for (int s = 0; s < NTILES; ++s) {
        // ===== P0: rbf A-fragments (params read from LDS, transient) =====
        bf8 a0, a1;
        {
            const float dd = dist_b[eArow + s * 4];
            const vf8 gla = *(const vf8*)&prm[0][g * 8];
            const vf8 glb = *(const vf8*)&prm[0][32 + g * 8];
            const vf8 cla = *(const vf8*)&prm[1][g * 8];
            const vf8 clb = *(const vf8*)&prm[1][32 + g * 8];
            u32x4 qa, qb;
            #pragma unroll
            for (int p = 0; p < 4; ++p) {
                float x0 = dd - cla[2 * p];     float v0 = __builtin_amdgcn_exp2f(-gla[2 * p]     * x0 * x0);
                float x1 = dd - cla[2 * p + 1]; float v1 = __builtin_amdgcn_exp2f(-gla[2 * p + 1] * x1 * x1);
                qa[p] = pack2(v1, v0);
                float y0 = dd - clb[2 * p];     float u0 = __builtin_amdgcn_exp2f(-glb[2 * p]     * y0 * y0);
                float y1 = dd - clb[2 * p + 1]; float u1 = __builtin_amdgcn_exp2f(-glb[2 * p + 1] * y1 * y1);
                qb[p] = pack2(u1, u0);
            }
            a0 = __builtin_bit_cast(bf8, qa);
            a1 = __builtin_bit_cast(bf8, qb);
        }

        // ===== P1: GEMM1 (cols permuted: phys nt*16+c0 -> logical 8*c0+nt) =====
        f32x4 hh[8];
        #pragma unroll
        for (int nt = 0; nt < 8; ++nt) {
            const bf8 w0 = *(const bf8*)&W1f[((0 * 4 + g) * D_ + nt * 16 + c0) * 8];
            const bf8 w1 = *(const bf8*)&W1f[((1 * 4 + g) * D_ + nt * 16 + c0) * 8];
            f32x4 acc = {0.f, 0.f, 0.f, 0.f};
            acc = __builtin_amdgcn_mfma_f32_16x16x32_bf16(a0, w0, acc, 0, 0, 0);
            acc = __builtin_amdgcn_mfma_f32_16x16x32_bf16(a1, w1, acc, 0, 0, 0);
            hh[nt] = acc;
        }

        // ===== P2: ssp + pack + swizzled b128 store to per-wave A2 =====
        {
            const vf8 b1r = *(const vf8*)&bia[0][8 * c0];
            #pragma unroll
            for (int r = 0; r < 4; ++r) {
                u32x4 q;
                #pragma unroll
                for (int p = 0; p < 4; ++p) {
                    float v0 = ssp(hh[2 * p][r]     + b1r[2 * p]);
                    float v1 = ssp(hh[2 * p + 1][r] + b1r[2 * p + 1]);
                    q[p] = pack2(v1, v0);
                }
                const int mphys = (g * 4 + r) ^ (c0 & 7);
                *(bf8*)&A2[w][c0][mphys][0] = __builtin_bit_cast(bf8, q);
            }
        }
        __syncthreads();   // phase fence (R4 cadence): A2 store -> GEMM2

        // ===== P3: GEMM2 =====
        f32x4 facc[8];
        {
            bf8 pfr[4];
            #pragma unroll
            for (int cc = 0; cc < 4; ++cc) {
                const int kb = cc * 4 + g;
                pfr[cc] = *(const bf8*)&A2[w][kb][c0 ^ (kb & 7)][0];
            }
            #pragma unroll
            for (int nt = 0; nt < 8; ++nt) {
                f32x4 acc = {0.f, 0.f, 0.f, 0.f};
                #pragma unroll
                for (int cc = 0; cc < 4; ++cc) {
                    const bf8 wf = *(const bf8*)&W2f[((cc * 4 + g) * D_ + nt * 16 + c0) * 8];
                    acc = __builtin_amdgcn_mfma_f32_16x16x32_bf16(pfr[cc], wf, acc, 0, 0, 0);
                }
                facc[nt] = acc;
            }
        }

        // ===== P4: epilogue — gather, ssp, sorted-run combine, atomics =====
        {
            const int e4 = ebase + s * 4;
            const int4 jv = *(const int4*)&idx_j[e4];
            const int4 sv = *(const int4*)&seg_i[e4];
            const vf8 b2r = *(const vf8*)&bia[1][8 * c0];
            #define EDGE_STEP(R, JJ, SG)                                        \
            {                                                                   \
                const vf8 nb = *(const vf8*)&af_b[(size_t)(JJ) * D_ + 8 * c0];  \
                vf8 msg;                                                        \
                _Pragma("unroll")                                               \
                for (int nt = 0; nt < 8; ++nt) {                                \
                    const float fv = ssp(facc[nt][R] + b2r[nt]);                \
                    msg[nt] = nb[nt] * fv;                                      \
                }                                                               \
                if ((SG) != cur_seg) {                                          \
                    if (cur_seg >= 0) {                                         \
                        float* o = out_b + (size_t)cur_seg * D_ + 8 * c0;       \
                        _Pragma("unroll")                                       \
                        for (int nt = 0; nt < 8; ++nt) atomicAdd(o + nt, pend[nt]); \
                    }                                                           \
                    cur_seg = (SG);                                             \
                    pend = msg;                                                 \
                } else {                                                        \
                    pend += msg;                                                \
                }                                                               \
            }
            EDGE_STEP(0, jv.x, sv.x)
            EDGE_STEP(1, jv.y, sv.y)
            EDGE_STEP(2, jv.z, sv.z)
            EDGE_STEP(3, jv.w, sv.w)
            #undef EDGE_STEP
        }
        __syncthreads();   // phase fence (R4 cadence): end of tile
    }
    if (cur_seg >= 0) {
        float* o = out_b + (size_t)cur_seg * D_ + 8 * c0;
        #pragma unroll
        for (int nt = 0; nt < 8; ++nt) atomicAdd(o + nt, pend[nt]);
    }
}

extern "C" void kernel_launch(void* const* d_in, const int* in_sizes, int n_in,
                              void* d_out, int out_size, void* d_ws, size_t ws_size,
                              hipStream_t stream) {
    const float* af      = (const float*)d_in[0];
    const float* dist    = (const float*)d_in[1];
    const int*   idx_j   = (const int*)d_in[2];
    const int*   seg_i   = (const int*)d_in[3];
    const float* centers = (const float*)d_in[4];
    const float* gam     = (const float*)d_in[5];
    const float* W1      = (const float*)d_in[6];
    const float* b1      = (const float*)d_in[7];
    const float* W2      = (const float*)d_in[8];
    const float* b2      = (const float*)d_in[9];
    float* out = (float*)d_out;

    hipMemsetAsync(out, 0, (size_t)out_size * sizeof(float), stream);

    dim3 grid(NBLK, B_);
    cfconv_kernel<<<grid, TPB, 0, stream>>>(af, dist, idx_j, seg_i,
                                            centers, gam, W1, b1, W2, b2, out);
}